// Round 1
// baseline (257.422 us; speedup 1.0000x reference)
//
#include <hip/hip_runtime.h>

// Integrate-and-fire over time axis.
// x: [T=32, N=4194304] fp32, out spikes same shape.
// Each thread owns 4 consecutive neurons (float4), scans T in registers.

#define T_STEPS 32

__global__ __launch_bounds__(256) void if_scan_kernel(
    const float4* __restrict__ x, float4* __restrict__ out, int nvec) {
    int i = blockIdx.x * blockDim.x + threadIdx.x;
    if (i >= nvec) return;

    float mx = 0.f, my = 0.f, mz = 0.f, mw = 0.f;

#pragma unroll
    for (int t = 0; t < T_STEPS; ++t) {
        int idx = t * nvec + i;           // < 2^25, fits int
        float4 xt = x[idx];
        mx += xt.x; my += xt.y; mz += xt.z; mw += xt.w;

        float4 s;
        s.x = (mx >= 1.0f) ? 1.0f : 0.0f;
        s.y = (my >= 1.0f) ? 1.0f : 0.0f;
        s.z = (mz >= 1.0f) ? 1.0f : 0.0f;
        s.w = (mw >= 1.0f) ? 1.0f : 0.0f;

        // hard reset where spiked
        mx = (s.x != 0.0f) ? 0.0f : mx;
        my = (s.y != 0.0f) ? 0.0f : my;
        mz = (s.z != 0.0f) ? 0.0f : mz;
        mw = (s.w != 0.0f) ? 0.0f : mw;

        out[idx] = s;
    }
}

extern "C" void kernel_launch(void* const* d_in, const int* in_sizes, int n_in,
                              void* d_out, int out_size, void* d_ws, size_t ws_size,
                              hipStream_t stream) {
    const float* x = (const float*)d_in[0];
    float* out = (float*)d_out;

    const long long total = (long long)in_sizes[0];   // T*N = 134217728
    const int N = (int)(total / T_STEPS);             // 4194304 neurons
    const int nvec = N / 4;                           // 1048576 float4 columns

    const int block = 256;
    const int grid = (nvec + block - 1) / block;      // 4096

    if_scan_kernel<<<grid, block, 0, stream>>>(
        (const float4*)x, (float4*)out, nvec);
}

// Round 3
// 238.954 us; speedup vs baseline: 1.0773x; 1.0773x over previous
//
#include <hip/hip_runtime.h>

// Integrate-and-fire scan over time axis.
// x: [T=32, N=4194304] fp32 -> spikes same shape.
// Each thread owns 4 consecutive neurons (one 16B vector column), scans T
// with the membrane in registers. Moderate unroll (8) for memory-level
// parallelism without blowing the VGPR budget; nontemporal hints since
// every byte is touched exactly once.

#define T_STEPS 32

typedef float f32x4 __attribute__((ext_vector_type(4)));

__global__ __launch_bounds__(256) void if_scan_kernel(
    const f32x4* __restrict__ x, f32x4* __restrict__ out, int nvec) {
    int i = blockIdx.x * blockDim.x + threadIdx.x;
    if (i >= nvec) return;

    const f32x4* __restrict__ px = x + i;
    f32x4* __restrict__ po = out + i;

    float mx = 0.f, my = 0.f, mz = 0.f, mw = 0.f;

#pragma unroll 8
    for (int t = 0; t < T_STEPS; ++t) {
        f32x4 xt = __builtin_nontemporal_load(&px[(size_t)t * nvec]);

        mx += xt.x; my += xt.y; mz += xt.z; mw += xt.w;

        f32x4 s;
        s.x = (mx >= 1.0f) ? 1.0f : 0.0f;
        s.y = (my >= 1.0f) ? 1.0f : 0.0f;
        s.z = (mz >= 1.0f) ? 1.0f : 0.0f;
        s.w = (mw >= 1.0f) ? 1.0f : 0.0f;

        mx = (s.x != 0.0f) ? 0.0f : mx;
        my = (s.y != 0.0f) ? 0.0f : my;
        mz = (s.z != 0.0f) ? 0.0f : mz;
        mw = (s.w != 0.0f) ? 0.0f : mw;

        __builtin_nontemporal_store(s, &po[(size_t)t * nvec]);
    }
}

extern "C" void kernel_launch(void* const* d_in, const int* in_sizes, int n_in,
                              void* d_out, int out_size, void* d_ws, size_t ws_size,
                              hipStream_t stream) {
    const float* x = (const float*)d_in[0];
    float* out = (float*)d_out;

    const long long total = (long long)in_sizes[0];   // T*N = 134217728
    const int N = (int)(total / T_STEPS);             // 4194304 neurons
    const int nvec = N / 4;                           // 1048576 columns

    const int block = 256;
    const int grid = (nvec + block - 1) / block;      // 4096 blocks

    if_scan_kernel<<<grid, block, 0, stream>>>(
        (const f32x4*)x, (f32x4*)out, nvec);
}